// Round 6
// baseline (437.657 us; speedup 1.0000x reference)
//
#include <hip/hip_runtime.h>
#include <hip/hip_bf16.h>
#include <math.h>

#define BATCH   131072
#define NCLASS  1000
#define FDIM    512
#define NTILE   136                  // 16*17/2 upper-tri 64x64 tiles
#define NRCHUNK 16
#define NDCHUNK 16
#define DSLICE  32
#define ROWS_PER (BATCH / NRCHUNK)   // 8192

typedef __attribute__((ext_vector_type(4))) float f32x4;
typedef __attribute__((ext_vector_type(8))) short short8;

// ws layout (bytes):
//  0         int   counts[1024]
//  4096      float accs[2]      {sum_dist_init, sum_hinge}
//  4104      int   done         KD ticket
//  12288     float pbuf[16][1000][512]   (32.77 MB)
//  33566720  float wsM[1000][512]        (aligned copy of new centers)
// memset covers [0, 8192).

__device__ __forceinline__ ushort f2bf(float x) {
    union { float f; unsigned u; } v; v.f = x;
    unsigned r = v.u + 0x7fff + ((v.u >> 16) & 1);   // RNE (finite inputs)
    return (ushort)(r >> 16);
}

// ---- MFMA dist tile: 64x64 Gram tile in bf16, norms inline from fp32 -------
// MODE 0: sum of dist -> accs[0].  MODE 1: sum of hinge -> accs[1].
template <int MODE>
__device__ void dist_mfma(const float* __restrict__ M, float th, int by, int bx,
                          float* __restrict__ accs) {
    __shared__ ushort Abf[64][72];      // 144B row stride: ds_read_b128 2-way free
    __shared__ ushort Bbf[64][72];
    __shared__ float  rnA[64];
    __shared__ float  rnB[64];
    __shared__ float  red[256];

    const int tid  = threadIdx.x;
    const int lane = tid & 63;
    const int w    = tid >> 6;          // wave 0..3
    const int wr   = w >> 1, wc = w & 1;
    const int row4 = tid >> 2;          // 0..63: staged row
    const int cq   = tid & 3;           // 4 threads/row, 16 cols each per k0
    const int gi_s = by * 64 + row4;
    const int gj_s = bx * 64 + row4;

    f32x4 acc[2][2];
#pragma unroll
    for (int m = 0; m < 2; ++m)
#pragma unroll
        for (int n = 0; n < 2; ++n) acc[m][n] = (f32x4){0.f, 0.f, 0.f, 0.f};

    float nA = 0.f, nB = 0.f;
    for (int k0 = 0; k0 < 8; ++k0) {
        __syncthreads();
#pragma unroll
        for (int c = 0; c < 4; ++c) {
            const int col  = cq * 16 + c * 4;
            const int gcol = k0 * 64 + col;
            f32x4 av = (f32x4){0.f, 0.f, 0.f, 0.f};
            f32x4 bv = (f32x4){0.f, 0.f, 0.f, 0.f};
            if (gi_s < NCLASS) av = *(const f32x4*)&M[(size_t)gi_s * FDIM + gcol];
            if (gj_s < NCLASS) bv = *(const f32x4*)&M[(size_t)gj_s * FDIM + gcol];
            nA += av.x * av.x + av.y * av.y + av.z * av.z + av.w * av.w;
            nB += bv.x * bv.x + bv.y * bv.y + bv.z * bv.z + bv.w * bv.w;
            ushort4 ap, bp;
            ap.x = f2bf(av.x); ap.y = f2bf(av.y); ap.z = f2bf(av.z); ap.w = f2bf(av.w);
            bp.x = f2bf(bv.x); bp.y = f2bf(bv.y); bp.z = f2bf(bv.z); bp.w = f2bf(bv.w);
            *(ushort4*)&Abf[row4][col] = ap;
            *(ushort4*)&Bbf[row4][col] = bp;
        }
        __syncthreads();
#pragma unroll
        for (int kk = 0; kk < 2; ++kk) {
            short8 a[2], b[2];
#pragma unroll
            for (int m = 0; m < 2; ++m)
                a[m] = *(const short8*)&Abf[wr * 32 + m * 16 + (lane & 15)]
                                          [kk * 32 + (lane >> 4) * 8];
#pragma unroll
            for (int n = 0; n < 2; ++n)
                b[n] = *(const short8*)&Bbf[wc * 32 + n * 16 + (lane & 15)]
                                          [kk * 32 + (lane >> 4) * 8];
#pragma unroll
            for (int m = 0; m < 2; ++m)
#pragma unroll
                for (int n = 0; n < 2; ++n)
                    acc[m][n] = __builtin_amdgcn_mfma_f32_16x16x32_bf16(
                        a[m], b[n], acc[m][n], 0, 0, 0);
        }
    }

    // reduce norms across the 4 threads/row (consecutive lanes: xor 1,2)
    nA += __shfl_xor(nA, 1, 64); nA += __shfl_xor(nA, 2, 64);
    nB += __shfl_xor(nB, 1, 64); nB += __shfl_xor(nB, 2, 64);
    if (cq == 0) { rnA[row4] = nA; rnB[row4] = nB; }
    __syncthreads();

    // epilogue: C/D map col=lane&15, row=(lane>>4)*4+i  [m89-verified]
    float local = 0.f;
#pragma unroll
    for (int m = 0; m < 2; ++m)
#pragma unroll
        for (int n = 0; n < 2; ++n)
#pragma unroll
            for (int i = 0; i < 4; ++i) {
                const int r_l = wr * 32 + m * 16 + (lane >> 4) * 4 + i;
                const int c_l = wc * 32 + n * 16 + (lane & 15);
                const int gi = by * 64 + r_l;
                const int gj = bx * 64 + c_l;
                if (gi < NCLASS && gj < NCLASS && gj > gi) {
                    float d2 = rnA[r_l] + rnB[c_l] - 2.0f * acc[m][n][i];
                    d2 = fmaxf(d2, 0.0f);
                    float dst = (d2 > 0.0f) ? sqrtf(d2) : 0.0f;
                    if (MODE == 1) {
                        if (dst < th) local += th - dst;
                    } else {
                        local += dst;
                    }
                }
            }

    red[tid] = local;
    __syncthreads();
    for (int s = 128; s > 0; s >>= 1) {
        if (tid < s) red[tid] += red[tid + s];
        __syncthreads();
    }
    if (tid == 0) atomicAdd(&accs[MODE], red[0]);
}

// ---- KA: blocks 0..135 dist0 tiles; blocks 136..263 bincount ---------------
__global__ __launch_bounds__(256)
void ka_dist0_bincount(const float* __restrict__ center,
                       const int* __restrict__ labels,
                       int* __restrict__ counts,
                       float* __restrict__ accs) {
    const int b = blockIdx.x;
    if (b < NTILE) {
        int idx = b;
        int by = 0;
        while (idx >= 16 - by) { idx -= 16 - by; ++by; }
        dist_mfma<0>(center, 0.0f, by, by + idx, accs);
        return;
    }
    const int gid = (b - NTILE) * 256 + threadIdx.x;
    int4 l = ((const int4*)labels)[gid];
    atomicAdd(&counts[l.x], 1);
    atomicAdd(&counts[l.y], 1);
    atomicAdd(&counts[l.z], 1);
    atomicAdd(&counts[l.w], 1);
}

// ---- KB: streaming dim-tiled LDS histogram ---------------------------------
// grid 256 = 16 row-chunks x 16 dim-slices; dynamic LDS hist[1000][33].
__global__ __launch_bounds__(256)
void kb_hist(const float* __restrict__ features,
             const int* __restrict__ labels,
             float* __restrict__ pbuf) {
    extern __shared__ float hist[];          // 1000*33 floats = 132000 B
    __shared__ int lab_s[256];
    const int b  = blockIdx.x;
    const int dt = b & 15;
    const int rt = b >> 4;
    const int t  = threadIdx.x;
    const int dbase = dt * DSLICE;
    const int row0  = rt * ROWS_PER;

    for (int i = t; i < NCLASS * 33; i += 256) hist[i] = 0.f;
    __syncthreads();

    const int rsub8 = t >> 3;                // 0..31: row within 32-group
    const int dq    = (t & 7) * 4;           // dim quad within slice
    for (int chunk = 0; chunk < ROWS_PER / 256; ++chunk) {
        __syncthreads();
        lab_s[t] = labels[row0 + chunk * 256 + t];
        __syncthreads();
#pragma unroll
        for (int it = 0; it < 8; ++it) {
            const int rs = it * 32 + rsub8;
            const int r  = row0 + chunk * 256 + rs;
            f32x4 v = *(const f32x4*)&features[(size_t)r * FDIM + dbase + dq];
            const int base = lab_s[rs] * 33 + dq;
            atomicAdd(&hist[base + 0], v.x);
            atomicAdd(&hist[base + 1], v.y);
            atomicAdd(&hist[base + 2], v.z);
            atomicAdd(&hist[base + 3], v.w);
        }
    }
    __syncthreads();

    for (int i = t; i < NCLASS * DSLICE; i += 256) {
        const int c = i >> 5, d = i & 31;
        pbuf[((size_t)rt * NCLASS + c) * FDIM + dbase + d] = hist[c * 33 + d];
    }
}

// ---- KC: finalize new centers ----------------------------------------------
__global__ __launch_bounds__(128)
void kc_finalize(const float* __restrict__ center,
                 const float* __restrict__ pbuf,
                 const int* __restrict__ counts,
                 float* __restrict__ out_center,
                 float* __restrict__ wsM) {
    const int c = blockIdx.x, t = threadIdx.x;
    f32x4 s = (f32x4){0.f, 0.f, 0.f, 0.f};
#pragma unroll
    for (int rt = 0; rt < NRCHUNK; ++rt)
        s += *(const f32x4*)&pbuf[((size_t)rt * NCLASS + c) * FDIM + t * 4];
    f32x4 cc = *(const f32x4*)&center[(size_t)c * FDIM + t * 4];
    const float invn = 1.0f / fmaxf((float)counts[c], 1.0f);
    f32x4 nc = (cc + s) * invn;
    float* o = out_center + (size_t)c * FDIM + t * 4;   // +1-float base: scalar stores
    o[0] = nc.x; o[1] = nc.y; o[2] = nc.z; o[3] = nc.w;
    *(f32x4*)&wsM[(size_t)c * FDIM + t * 4] = nc;
}

// ---- KD: dist1 tiles + ticket loss finalize --------------------------------
__global__ __launch_bounds__(256)
void kd_dist1(const float* __restrict__ wsM, float* __restrict__ accs,
              int* __restrict__ done, float* __restrict__ out0) {
    int idx = blockIdx.x;
    int by = 0;
    while (idx >= 16 - by) { idx -= 16 - by; ++by; }
    const float th = 6.0f * accs[0] * 1e-6f;
    dist_mfma<1>(wsM, th, by, by + idx, accs);
    if (threadIdx.x == 0) {
        __threadfence();
        if (atomicAdd(done, 1) == NTILE - 1) {
            __threadfence();
            const float l1 = atomicAdd(&accs[1], 0.0f);
            const double thd = 6.0 * (double)accs[0] * 1e-6;
            out0[0] = (float)((2.0 * (double)l1 + (double)NCLASS * thd) * 1e-6);
        }
    }
}

extern "C" void kernel_launch(void* const* d_in, const int* in_sizes, int n_in,
                              void* d_out, int out_size, void* d_ws, size_t ws_size,
                              hipStream_t stream) {
    const float* features = (const float*)d_in[0];
    const float* center   = (const float*)d_in[1];
    const int*   labels   = (const int*)d_in[2];
    float* out = (float*)d_out;
    char*  ws  = (char*)d_ws;

    int*   counts = (int*)(ws + 0);
    float* accs   = (float*)(ws + 4096);
    int*   done   = (int*)(ws + 4104);
    float* pbuf   = (float*)(ws + 12288);
    float* wsM    = (float*)(ws + 33566720);

    hipMemsetAsync(ws, 0, 8192, stream);
    ka_dist0_bincount<<<NTILE + BATCH / 1024, 256, 0, stream>>>(center, labels,
                                                                counts, accs);
    kb_hist<<<NRCHUNK * NDCHUNK, 256, 33 * NCLASS * 4, stream>>>(features, labels,
                                                                 pbuf);
    kc_finalize<<<NCLASS, 128, 0, stream>>>(center, pbuf, counts, out + 1, wsM);
    kd_dist1<<<NTILE, 256, 0, stream>>>(wsM, accs, done, out);
}

// Round 8
// 153.380 us; speedup vs baseline: 2.8534x; 2.8534x over previous
//
#include <hip/hip_runtime.h>
#include <hip/hip_bf16.h>
#include <math.h>

#define BATCH   131072
#define NCLASS  1000
#define FDIM    512
#define NTILE   136                  // 16*17/2 upper-tri 64x64 tiles

typedef __attribute__((ext_vector_type(4))) float f32x4;
typedef __attribute__((ext_vector_type(8))) short short8;

// ws layout (bytes):
//  0        int   counts[1024]
//  4096     int   cursor0[1024]
//  8192     float accs[2]      {sum_dist_init, sum_hinge}
//  8200     int   done         K5 ticket
//  12288    int   g_offsets[1024]
//  16384    int   perm[131072]         ends 540672
//  544768   float pbuf[4][1000][512]   ends 8736768
//  8740864  float wsM[1000][512]       ends 10788864
// memset covers [0, 8208).
#define OFF_COUNTS   0
#define OFF_CURSOR   4096
#define OFF_ACCS     8192
#define OFF_DONE     8200
#define OFF_GOFFS    12288
#define OFF_PERM     16384
#define OFF_PBUF     544768
#define OFF_WSM      8740864
static_assert(OFF_PERM + BATCH * 4 <= OFF_PBUF, "perm/pbuf overlap");
static_assert(OFF_PBUF + 4 * NCLASS * FDIM * 4 <= OFF_WSM, "pbuf/wsM overlap");
static_assert(OFF_GOFFS + 4096 <= OFF_PERM, "goffs/perm overlap");

__device__ __forceinline__ ushort f2bf(float x) {
    union { float f; unsigned u; } v; v.f = x;
    unsigned r = v.u + 0x7fff + ((v.u >> 16) & 1);   // RNE (finite inputs)
    return (ushort)(r >> 16);
}

// ---- MFMA dist tile: 64x64 Gram tile in bf16, norms inline from fp32 -------
// MODE 0: sum of dist -> accs[0].  MODE 1: sum of hinge -> accs[1].
template <int MODE>
__device__ void dist_mfma(const float* __restrict__ M, float th, int by, int bx,
                          float* __restrict__ accs) {
    __shared__ ushort Abf[64][72];      // 144B row stride: ds_read_b128 2-way free
    __shared__ ushort Bbf[64][72];
    __shared__ float  rnA[64];
    __shared__ float  rnB[64];
    __shared__ float  red[256];

    const int tid  = threadIdx.x;
    const int lane = tid & 63;
    const int w    = tid >> 6;          // wave 0..3
    const int wr   = w >> 1, wc = w & 1;
    const int row4 = tid >> 2;          // 0..63: staged row
    const int cq   = tid & 3;           // 4 threads/row, 16 cols each per k0
    const int gi_s = by * 64 + row4;
    const int gj_s = bx * 64 + row4;

    f32x4 acc[2][2];
#pragma unroll
    for (int m = 0; m < 2; ++m)
#pragma unroll
        for (int n = 0; n < 2; ++n) acc[m][n] = (f32x4){0.f, 0.f, 0.f, 0.f};

    float nA = 0.f, nB = 0.f;
    for (int k0 = 0; k0 < 8; ++k0) {
        __syncthreads();
#pragma unroll
        for (int c = 0; c < 4; ++c) {
            const int col  = cq * 16 + c * 4;
            const int gcol = k0 * 64 + col;
            f32x4 av = (f32x4){0.f, 0.f, 0.f, 0.f};
            f32x4 bv = (f32x4){0.f, 0.f, 0.f, 0.f};
            if (gi_s < NCLASS) av = *(const f32x4*)&M[(size_t)gi_s * FDIM + gcol];
            if (gj_s < NCLASS) bv = *(const f32x4*)&M[(size_t)gj_s * FDIM + gcol];
            nA += av.x * av.x + av.y * av.y + av.z * av.z + av.w * av.w;
            nB += bv.x * bv.x + bv.y * bv.y + bv.z * bv.z + bv.w * bv.w;
            ushort4 ap, bp;
            ap.x = f2bf(av.x); ap.y = f2bf(av.y); ap.z = f2bf(av.z); ap.w = f2bf(av.w);
            bp.x = f2bf(bv.x); bp.y = f2bf(bv.y); bp.z = f2bf(bv.z); bp.w = f2bf(bv.w);
            *(ushort4*)&Abf[row4][col] = ap;
            *(ushort4*)&Bbf[row4][col] = bp;
        }
        __syncthreads();
#pragma unroll
        for (int kk = 0; kk < 2; ++kk) {
            short8 a[2], b[2];
#pragma unroll
            for (int m = 0; m < 2; ++m)
                a[m] = *(const short8*)&Abf[wr * 32 + m * 16 + (lane & 15)]
                                          [kk * 32 + (lane >> 4) * 8];
#pragma unroll
            for (int n = 0; n < 2; ++n)
                b[n] = *(const short8*)&Bbf[wc * 32 + n * 16 + (lane & 15)]
                                          [kk * 32 + (lane >> 4) * 8];
#pragma unroll
            for (int m = 0; m < 2; ++m)
#pragma unroll
                for (int n = 0; n < 2; ++n)
                    acc[m][n] = __builtin_amdgcn_mfma_f32_16x16x32_bf16(
                        a[m], b[n], acc[m][n], 0, 0, 0);
        }
    }

    nA += __shfl_xor(nA, 1, 64); nA += __shfl_xor(nA, 2, 64);
    nB += __shfl_xor(nB, 1, 64); nB += __shfl_xor(nB, 2, 64);
    if (cq == 0) { rnA[row4] = nA; rnB[row4] = nB; }
    __syncthreads();

    float local = 0.f;
#pragma unroll
    for (int m = 0; m < 2; ++m)
#pragma unroll
        for (int n = 0; n < 2; ++n)
#pragma unroll
            for (int i = 0; i < 4; ++i) {
                const int r_l = wr * 32 + m * 16 + (lane >> 4) * 4 + i;
                const int c_l = wc * 32 + n * 16 + (lane & 15);
                const int gi = by * 64 + r_l;
                const int gj = bx * 64 + c_l;
                if (gi < NCLASS && gj < NCLASS && gj > gi) {
                    float d2 = rnA[r_l] + rnB[c_l] - 2.0f * acc[m][n][i];
                    d2 = fmaxf(d2, 0.0f);
                    float dst = (d2 > 0.0f) ? sqrtf(d2) : 0.0f;
                    if (MODE == 1) {
                        if (dst < th) local += th - dst;
                    } else {
                        local += dst;
                    }
                }
            }

    red[tid] = local;
    __syncthreads();
    for (int s = 128; s > 0; s >>= 1) {
        if (tid < s) red[tid] += red[tid + s];
        __syncthreads();
    }
    if (tid == 0) atomicAdd(&accs[MODE], red[0]);
}

// ---- KA: blocks 0..135 dist0 tiles; blocks 136..263 bincount ---------------
__global__ __launch_bounds__(256)
void ka_dist0_bincount(const float* __restrict__ center,
                       const int* __restrict__ labels,
                       int* __restrict__ counts,
                       float* __restrict__ accs) {
    const int b = blockIdx.x;
    if (b < NTILE) {
        int idx = b;
        int by = 0;
        while (idx >= 16 - by) { idx -= 16 - by; ++by; }
        dist_mfma<0>(center, 0.0f, by, by + idx, accs);
        return;
    }
    const int gid = (b - NTILE) * 256 + threadIdx.x;
    int4 l = ((const int4*)labels)[gid];
    atomicAdd(&counts[l.x], 1);
    atomicAdd(&counts[l.y], 1);
    atomicAdd(&counts[l.z], 1);
    atomicAdd(&counts[l.w], 1);
}

// ---- K2: per-block redundant LDS scan of counts + scatter ------------------
__global__ __launch_bounds__(256)
void k2_scan_scatter(const int* __restrict__ labels, const int* __restrict__ counts,
                     int* __restrict__ cursor0, int* __restrict__ perm,
                     int* __restrict__ g_offsets) {
    __shared__ int sA[1024];
    __shared__ int sB[1024];
    const int b = blockIdx.x, t = threadIdx.x;
    for (int i = t; i < 1024; i += 256) sA[i] = counts[i];
    __syncthreads();
    int* cur = sA;
    int* nxt = sB;
    for (int off = 1; off < 1024; off <<= 1) {
        for (int i = t; i < 1024; i += 256) {
            int v = cur[i];
            if (i >= off) v += cur[i - off];
            nxt[i] = v;
        }
        __syncthreads();
        int* tmp = cur; cur = nxt; nxt = tmp;
    }
    int* offp = nxt;
    for (int i = t; i < 1024; i += 256) offp[i] = i ? cur[i - 1] : 0;
    __syncthreads();
    if (b == 0)
        for (int i = t; i < 1024; i += 256) g_offsets[i] = offp[i];
    const int gid = b * 256 + t;
    int4 l = ((const int4*)labels)[gid];
    const int r = gid * 4;
    perm[offp[l.x] + atomicAdd(&cursor0[l.x], 1)] = r + 0;
    perm[offp[l.y] + atomicAdd(&cursor0[l.y], 1)] = r + 1;
    perm[offp[l.z] + atomicAdd(&cursor0[l.z], 1)] = r + 2;
    perm[offp[l.w] + atomicAdd(&cursor0[l.w], 1)] = r + 3;
}

// ---- K3: MLP-maximized gather ---------------------------------------------
// grid (1000, 2) x 256. half = t>>7 picks row parity (wave-uniform); 16 rows
// (8/thread) in flight per unrolled step; perm via wave-uniform s_loads; no
// LDS, no syncs. Each half writes its own pbuf slot (q*2+half).
__global__ __launch_bounds__(256)
void k3_gather(const float* __restrict__ features,
               const int* __restrict__ g_offsets,
               const int* __restrict__ counts,
               const int* __restrict__ perm,
               float* __restrict__ pbuf) {
    const int c = blockIdx.x, q = blockIdx.y, t = threadIdx.x;
    const int half = t >> 7;
    const int pos  = t & 127;
    const int beg = g_offsets[c], n = counts[c];
    const int per = (n + 1) >> 1;
    const int s0  = q * per;
    const int e0  = min(n, s0 + per);
    const int cnt = e0 - s0;
    const int* pp = perm + beg + s0;

    f32x4 acc = (f32x4){0.f, 0.f, 0.f, 0.f};
    int r = half;
    for (; r + 14 < cnt; r += 16) {
        const int i0 = pp[r + 0],  i1 = pp[r + 2],  i2 = pp[r + 4],  i3 = pp[r + 6];
        const int i4 = pp[r + 8],  i5 = pp[r + 10], i6 = pp[r + 12], i7 = pp[r + 14];
        f32x4 v0 = *(const f32x4*)&features[(size_t)i0 * FDIM + pos * 4];
        f32x4 v1 = *(const f32x4*)&features[(size_t)i1 * FDIM + pos * 4];
        f32x4 v2 = *(const f32x4*)&features[(size_t)i2 * FDIM + pos * 4];
        f32x4 v3 = *(const f32x4*)&features[(size_t)i3 * FDIM + pos * 4];
        f32x4 v4 = *(const f32x4*)&features[(size_t)i4 * FDIM + pos * 4];
        f32x4 v5 = *(const f32x4*)&features[(size_t)i5 * FDIM + pos * 4];
        f32x4 v6 = *(const f32x4*)&features[(size_t)i6 * FDIM + pos * 4];
        f32x4 v7 = *(const f32x4*)&features[(size_t)i7 * FDIM + pos * 4];
        acc += ((v0 + v1) + (v2 + v3)) + ((v4 + v5) + (v6 + v7));
    }
    for (; r < cnt; r += 2) {
        acc += *(const f32x4*)&features[(size_t)pp[r] * FDIM + pos * 4];
    }
    const int slot = q * 2 + half;
    *(f32x4*)&pbuf[((size_t)slot * NCLASS + c) * FDIM + pos * 4] = acc;
}

// ---- K4: finalize new centers ----------------------------------------------
__global__ __launch_bounds__(128)
void k4_finalize(const float* __restrict__ center,
                 const float* __restrict__ pbuf,
                 const int* __restrict__ counts,
                 float* __restrict__ out_center,
                 float* __restrict__ wsM) {
    const int c = blockIdx.x, t = threadIdx.x;
    f32x4 s = (f32x4){0.f, 0.f, 0.f, 0.f};
#pragma unroll
    for (int slot = 0; slot < 4; ++slot)
        s += *(const f32x4*)&pbuf[((size_t)slot * NCLASS + c) * FDIM + t * 4];
    f32x4 cc = *(const f32x4*)&center[(size_t)c * FDIM + t * 4];
    const float invn = 1.0f / fmaxf((float)counts[c], 1.0f);
    f32x4 nc = (cc + s) * invn;
    float* o = out_center + (size_t)c * FDIM + t * 4;   // +1-float base: scalar stores
    o[0] = nc.x; o[1] = nc.y; o[2] = nc.z; o[3] = nc.w;
    *(f32x4*)&wsM[(size_t)c * FDIM + t * 4] = nc;
}

// ---- K5: dist1 tiles + ticket loss finalize --------------------------------
__global__ __launch_bounds__(256)
void k5_dist1(const float* __restrict__ wsM, float* __restrict__ accs,
              int* __restrict__ done, float* __restrict__ out0) {
    int idx = blockIdx.x;
    int by = 0;
    while (idx >= 16 - by) { idx -= 16 - by; ++by; }
    const float th = 6.0f * accs[0] * 1e-6f;
    dist_mfma<1>(wsM, th, by, by + idx, accs);
    if (threadIdx.x == 0) {
        __threadfence();
        if (atomicAdd(done, 1) == NTILE - 1) {
            __threadfence();
            const float l1 = atomicAdd(&accs[1], 0.0f);
            const double thd = 6.0 * (double)accs[0] * 1e-6;
            out0[0] = (float)((2.0 * (double)l1 + (double)NCLASS * thd) * 1e-6);
        }
    }
}

extern "C" void kernel_launch(void* const* d_in, const int* in_sizes, int n_in,
                              void* d_out, int out_size, void* d_ws, size_t ws_size,
                              hipStream_t stream) {
    const float* features = (const float*)d_in[0];
    const float* center   = (const float*)d_in[1];
    const int*   labels   = (const int*)d_in[2];
    float* out = (float*)d_out;
    char*  ws  = (char*)d_ws;

    int*   counts    = (int*)(ws + OFF_COUNTS);
    int*   cursor0   = (int*)(ws + OFF_CURSOR);
    float* accs      = (float*)(ws + OFF_ACCS);
    int*   done      = (int*)(ws + OFF_DONE);
    int*   g_offsets = (int*)(ws + OFF_GOFFS);
    int*   perm      = (int*)(ws + OFF_PERM);
    float* pbuf      = (float*)(ws + OFF_PBUF);
    float* wsM       = (float*)(ws + OFF_WSM);

    hipMemsetAsync(ws, 0, 8208, stream);
    ka_dist0_bincount<<<NTILE + BATCH / 1024, 256, 0, stream>>>(center, labels,
                                                                counts, accs);
    k2_scan_scatter<<<BATCH / 1024, 256, 0, stream>>>(labels, counts, cursor0,
                                                      perm, g_offsets);
    k3_gather<<<dim3(NCLASS, 2), 256, 0, stream>>>(features, g_offsets, counts,
                                                   perm, pbuf);
    k4_finalize<<<NCLASS, 128, 0, stream>>>(center, pbuf, counts, out + 1, wsM);
    k5_dist1<<<NTILE, 256, 0, stream>>>(wsM, accs, done, out);
}